// Round 1
// baseline (135.520 us; speedup 1.0000x reference)
//
#include <hip/hip_runtime.h>

// SimGRew: Wmat = relu(S - prob + 0.5*A_sel) * same-graph-block mask
//   S = (X_hat @ X_hat^T) / ||X_hat||_F^2,  X_hat = x @ W0^T + b0
//   A_sel[i,j] = A[batch[i], i, j]  (local-index adjacency; nonzero only i,j < NPG)
// Outputs flat: Wmat[N*N] f32, edge_ratio, prob.

#define NN   4096
#define GG   8
#define NPG  512
#define FF   128
#define HH   128
#define NE   131072
#define ALPHA 0.5f

// workspace layout (bytes)
#define XHAT_OFF  ((size_t)0)                          // float[NN*HH]        = 2 MiB
#define ACNT_OFF  ((size_t)2*1024*1024)                // int[GG*NPG*NPG]     = 8 MiB
#define META_OFF  (ACNT_OFF + (size_t)GG*NPG*NPG*4)    // offsets[8], norm, nz

__global__ __launch_bounds__(256) void k_offsets(const int* __restrict__ batch,
                                                 int* __restrict__ offs) {
    __shared__ int cnt[GG];
    int tid = threadIdx.x;
    if (tid < GG) cnt[tid] = 0;
    __syncthreads();
    for (int i = tid; i < NN; i += 256) atomicAdd(&cnt[batch[i]], 1);
    __syncthreads();
    if (tid == 0) {
        int run = 0;
        for (int g = 0; g < GG; ++g) { offs[g] = run; run += cnt[g]; }
    }
}

__global__ __launch_bounds__(256) void k_scatter(const int* __restrict__ ei,
                                                 const int* __restrict__ batch,
                                                 const int* __restrict__ offs,
                                                 int* __restrict__ Acnt) {
    int e = blockIdx.x * 256 + threadIdx.x;
    if (e >= NE) return;
    int src = ei[e], dst = ei[NE + e];
    int g  = batch[src];
    int lu = src - offs[g];
    int lv = dst - offs[batch[dst]];
    if (g >= 0 && g < GG && lu >= 0 && lu < NPG && lv >= 0 && lv < NPG)
        atomicAdd(&Acnt[((size_t)g * NPG + lu) * NPG + lv], 1);
}

// X_hat = x @ W0^T + b0 ; also accumulate ||X_hat||^2 into *normsq.
// 64x64 output tile per block, 16x16 threads, 4x4 acc/thread, K-chunks of 16.
__global__ __launch_bounds__(256) void k_xhat(const float* __restrict__ x,
                                              const float* __restrict__ W0,
                                              const float* __restrict__ b0,
                                              float* __restrict__ Xh,
                                              float* __restrict__ normsq) {
    __shared__ float As[16][68];   // k-major, padded row=68 (272B, 16B-aligned)
    __shared__ float Bs[16][68];
    __shared__ float red[256];

    int bx = blockIdx.x;                 // 64 m-tiles x 2 n-tiles = 128 blocks
    int tm = bx >> 1, tn = bx & 1;
    int r0 = tm * 64, j0 = tn * 64;
    int tid = threadIdx.x;
    int tx = tid & 15, ty = tid >> 4;
    int li = tid & 63, kq = tid >> 6;

    float acc[4][4];
#pragma unroll
    for (int i = 0; i < 4; ++i)
#pragma unroll
        for (int j = 0; j < 4; ++j) acc[i][j] = 0.f;

    for (int k0 = 0; k0 < FF; k0 += 16) {
        float4 av = *(const float4*)&x [(size_t)(r0 + li) * FF + k0 + kq * 4];
        float4 bv = *(const float4*)&W0[(size_t)(j0 + li) * FF + k0 + kq * 4];
        As[kq*4+0][li] = av.x; As[kq*4+1][li] = av.y;
        As[kq*4+2][li] = av.z; As[kq*4+3][li] = av.w;
        Bs[kq*4+0][li] = bv.x; Bs[kq*4+1][li] = bv.y;
        Bs[kq*4+2][li] = bv.z; Bs[kq*4+3][li] = bv.w;
        __syncthreads();
#pragma unroll
        for (int k = 0; k < 16; ++k) {
            float4 a = *(const float4*)&As[k][ty * 4];
            float4 b = *(const float4*)&Bs[k][tx * 4];
            float ar[4] = {a.x, a.y, a.z, a.w};
            float br[4] = {b.x, b.y, b.z, b.w};
#pragma unroll
            for (int i = 0; i < 4; ++i)
#pragma unroll
                for (int j = 0; j < 4; ++j) acc[i][j] += ar[i] * br[j];
        }
        __syncthreads();
    }

    float4 bb = *(const float4*)&b0[j0 + tx * 4];
    float ss = 0.f;
#pragma unroll
    for (int ii = 0; ii < 4; ++ii) {
        int row = r0 + ty * 4 + ii;
        float4 v;
        v.x = acc[ii][0] + bb.x;
        v.y = acc[ii][1] + bb.y;
        v.z = acc[ii][2] + bb.z;
        v.w = acc[ii][3] + bb.w;
        *(float4*)&Xh[(size_t)row * HH + j0 + tx * 4] = v;
        ss += v.x * v.x + v.y * v.y + v.z * v.z + v.w * v.w;
    }

    red[tid] = ss;
    __syncthreads();
    for (int s = 128; s > 0; s >>= 1) {
        if (tid < s) red[tid] += red[tid + s];
        __syncthreads();
    }
    if (tid == 0) atomicAdd(normsq, red[0]);
}

// Per-graph diagonal block: W = relu(Xh_g Xh_g^T / norm - prob + 0.5*Acnt), count nnz.
__global__ __launch_bounds__(256) void k_wmat(const float* __restrict__ Xh,
                                              const int* __restrict__ Acnt,
                                              const float* __restrict__ normsq,
                                              const float* __restrict__ prob,
                                              float* __restrict__ out,
                                              int* __restrict__ nz) {
    __shared__ float As[16][68];
    __shared__ float Bs[16][68];
    __shared__ int redi[256];

    int bx = blockIdx.x;                 // GG * 8 * 8 = 512 blocks
    int gb = bx >> 6;
    int t  = bx & 63;
    int tm = t >> 3, tn = t & 7;
    int base = gb * NPG;
    int r0 = base + tm * 64, c0 = base + tn * 64;
    int tid = threadIdx.x;
    int tx = tid & 15, ty = tid >> 4;
    int li = tid & 63, kq = tid >> 6;

    float acc[4][4];
#pragma unroll
    for (int i = 0; i < 4; ++i)
#pragma unroll
        for (int j = 0; j < 4; ++j) acc[i][j] = 0.f;

    for (int k0 = 0; k0 < HH; k0 += 16) {
        float4 av = *(const float4*)&Xh[(size_t)(r0 + li) * HH + k0 + kq * 4];
        float4 bv = *(const float4*)&Xh[(size_t)(c0 + li) * HH + k0 + kq * 4];
        As[kq*4+0][li] = av.x; As[kq*4+1][li] = av.y;
        As[kq*4+2][li] = av.z; As[kq*4+3][li] = av.w;
        Bs[kq*4+0][li] = bv.x; Bs[kq*4+1][li] = bv.y;
        Bs[kq*4+2][li] = bv.z; Bs[kq*4+3][li] = bv.w;
        __syncthreads();
#pragma unroll
        for (int k = 0; k < 16; ++k) {
            float4 a = *(const float4*)&As[k][ty * 4];
            float4 b = *(const float4*)&Bs[k][tx * 4];
            float ar[4] = {a.x, a.y, a.z, a.w};
            float br[4] = {b.x, b.y, b.z, b.w};
#pragma unroll
            for (int i = 0; i < 4; ++i)
#pragma unroll
                for (int j = 0; j < 4; ++j) acc[i][j] += ar[i] * br[j];
        }
        __syncthreads();
    }

    float inv = 1.0f / (*normsq);
    float p = prob[0];
    int cnt = 0;
#pragma unroll
    for (int ii = 0; ii < 4; ++ii) {
        int row = r0 + ty * 4 + ii;
        float4 v;
        float w[4];
#pragma unroll
        for (int jj = 0; jj < 4; ++jj) {
            int col = c0 + tx * 4 + jj;
            float s = acc[ii][jj] * inv;
            float a = 0.f;
            if (row < NPG && col < NPG)   // A_sel[row,col] = A[batch[row], row, col]
                a = (float)Acnt[((size_t)gb * NPG + row) * NPG + col];
            float pre = s - p + ALPHA * a;
            w[jj] = pre > 0.f ? pre : 0.f;
            cnt += (pre > 0.f) ? 1 : 0;
        }
        v.x = w[0]; v.y = w[1]; v.z = w[2]; v.w = w[3];
        *(float4*)&out[(size_t)row * NN + c0 + tx * 4] = v;
    }

    redi[tid] = cnt;
    __syncthreads();
    for (int s = 128; s > 0; s >>= 1) {
        if (tid < s) redi[tid] += redi[tid + s];
        __syncthreads();
    }
    if (tid == 0) atomicAdd(nz, redi[0]);
}

__global__ void k_fin(const int* __restrict__ nz, const float* __restrict__ prob,
                      float* __restrict__ out) {
    out[(size_t)NN * NN]     = (float)(*nz) / (float)NE;
    out[(size_t)NN * NN + 1] = prob[0];
}

extern "C" void kernel_launch(void* const* d_in, const int* in_sizes, int n_in,
                              void* d_out, int out_size, void* d_ws, size_t ws_size,
                              hipStream_t stream) {
    (void)in_sizes; (void)n_in; (void)out_size; (void)ws_size;
    const float* x    = (const float*)d_in[0];
    const float* W0   = (const float*)d_in[1];
    const float* b0   = (const float*)d_in[2];
    const float* prob = (const float*)d_in[3];
    const int*   ei   = (const int*)d_in[4];
    const int*   bat  = (const int*)d_in[5];
    float* out = (float*)d_out;
    char*  ws  = (char*)d_ws;

    float* Xh     = (float*)(ws + XHAT_OFF);
    int*   Acnt   = (int*)(ws + ACNT_OFF);
    int*   offs   = (int*)(ws + META_OFF);
    float* normsq = (float*)(ws + META_OFF + 32);
    int*   nz     = (int*)(ws + META_OFF + 36);

    // zero Wmat region of d_out, and Acnt + meta scratch
    hipMemsetAsync(out, 0, (size_t)NN * NN * sizeof(float), stream);
    hipMemsetAsync(ws + ACNT_OFF, 0, (size_t)GG * NPG * NPG * 4 + 64, stream);

    k_offsets<<<1, 256, 0, stream>>>(bat, offs);
    k_xhat<<<128, 256, 0, stream>>>(x, W0, b0, Xh, normsq);
    k_scatter<<<NE / 256, 256, 0, stream>>>(ei, bat, offs, Acnt);
    k_wmat<<<GG * 64, 256, 0, stream>>>(Xh, Acnt, normsq, prob, out, nz);
    k_fin<<<1, 1, 0, stream>>>(nz, prob, out);
}